// Round 1
// baseline (18747.783 us; speedup 1.0000x reference)
//
#include <hip/hip_runtime.h>
#include <hip/hip_bf16.h>
#include <math.h>

#define Bb 64
#define Tt 1024
#define Dd 128
#define Hh 256
#define G4 1024  // 4*H
#define Vv 128
#define NVh 3
#define BT (Bb*Tt)

// ---------------- Kernel A: gx[bt][j] = sum_d x[bt][d]*W_ih[j][d] + b_ih[j] + b_hh[j] ----
__global__ __launch_bounds__(256) void gx_gemm(const float* __restrict__ x,
                                               const float* __restrict__ Wih,
                                               const float* __restrict__ bih,
                                               const float* __restrict__ bhh,
                                               float* __restrict__ gx) {
    __shared__ float As[64][68];
    __shared__ float Ws[64][68];
    const int tid = threadIdx.x;
    const int tx = tid & 15, ty = tid >> 4;
    const int rb = blockIdx.x * 64;     // bt row base
    const int jb = blockIdx.y * 64;     // gate col base
    float acc[4][4] = {};
    for (int kb = 0; kb < Dd; kb += 64) {
        #pragma unroll
        for (int q = 0; q < 4; ++q) {
            int lin = q * 256 + tid;
            int row = lin >> 4;
            int c4 = (lin & 15) * 4;
            *(float4*)&As[row][c4] = *(const float4*)&x[(size_t)(rb + row) * Dd + kb + c4];
            *(float4*)&Ws[row][c4] = *(const float4*)&Wih[(size_t)(jb + row) * Dd + kb + c4];
        }
        __syncthreads();
        #pragma unroll 8
        for (int kk = 0; kk < 64; ++kk) {
            float a0 = As[ty*4+0][kk], a1 = As[ty*4+1][kk];
            float a2 = As[ty*4+2][kk], a3 = As[ty*4+3][kk];
            float w0 = Ws[tx*4+0][kk], w1 = Ws[tx*4+1][kk];
            float w2 = Ws[tx*4+2][kk], w3 = Ws[tx*4+3][kk];
            acc[0][0] += a0*w0; acc[0][1] += a0*w1; acc[0][2] += a0*w2; acc[0][3] += a0*w3;
            acc[1][0] += a1*w0; acc[1][1] += a1*w1; acc[1][2] += a1*w2; acc[1][3] += a1*w3;
            acc[2][0] += a2*w0; acc[2][1] += a2*w1; acc[2][2] += a2*w2; acc[2][3] += a2*w3;
            acc[3][0] += a3*w0; acc[3][1] += a3*w1; acc[3][2] += a3*w2; acc[3][3] += a3*w3;
        }
        __syncthreads();
    }
    const int col = jb + tx * 4;
    float bv0 = bih[col+0] + bhh[col+0];
    float bv1 = bih[col+1] + bhh[col+1];
    float bv2 = bih[col+2] + bhh[col+2];
    float bv3 = bih[col+3] + bhh[col+3];
    #pragma unroll
    for (int i = 0; i < 4; ++i) {
        int row = rb + ty * 4 + i;
        float4 r;
        r.x = acc[i][0] + bv0;
        r.y = acc[i][1] + bv1;
        r.z = acc[i][2] + bv2;
        r.w = acc[i][3] + bv3;
        *(float4*)&gx[(size_t)row * G4 + col] = r;
    }
}

// ---------------- Kernel B: persistent LSTM scan, one block per batch element ----
// thread j (0..1023) owns gate-row j of W_hh in 256 VGPRs. h lives in LDS,
// c in registers (threads j<H). Two __syncthreads per step, no grid sync.
__global__ __launch_bounds__(1024) void lstm_scan(const float* __restrict__ gx,
                                                  const float* __restrict__ Whh,
                                                  float* __restrict__ hs) {
    __shared__ __align__(16) float h_lds[Hh];
    __shared__ float g_lds[G4];
    const int j = threadIdx.x;
    const int b = blockIdx.x;

    // Load W_hh row j into registers (one-time; 64 blocks x 1MB, L2-amortized)
    float4 w[64];
    #pragma unroll
    for (int q = 0; q < 64; ++q)
        w[q] = *(const float4*)&Whh[(size_t)j * Hh + q * 4];

    float c = 0.f;
    if (j < Hh) h_lds[j] = 0.f;
    __syncthreads();

    const float* gxb = gx + (size_t)b * Tt * G4;
    float* hsb = hs + (size_t)b * Tt * Hh;

    for (int t = 0; t < Tt; ++t) {
        float g = gxb[(size_t)t * G4 + j];   // coalesced, issued early
        float sum = 0.f;
        #pragma unroll
        for (int q = 0; q < 64; ++q) {
            float4 hv = *(const float4*)&h_lds[q * 4];   // wave-uniform broadcast
            sum += w[q].x * hv.x;
            sum += w[q].y * hv.y;
            sum += w[q].z * hv.z;
            sum += w[q].w * hv.w;
        }
        g += sum;
        g_lds[j] = g;
        __syncthreads();   // g_lds complete; everyone done reading h_lds
        if (j < Hh) {
            float gi = g_lds[j];
            float gf = g_lds[j + Hh];
            float gg = g_lds[j + 2*Hh];
            float go = g_lds[j + 3*Hh];
            float si = 1.f / (1.f + __expf(-gi));
            float sf = 1.f / (1.f + __expf(-gf));
            float so = 1.f / (1.f + __expf(-go));
            float tg = tanhf(gg);
            c = sf * c + si * tg;
            float hn = so * tanhf(c);
            h_lds[j] = hn;
            hsb[(size_t)t * Hh + j] = hn;
        }
        __syncthreads();   // h_lds(t) visible for step t+1
    }
}

// ---------------- Kernel C: logits[n][bt][v] = sum_h hs[bt][h]*head_w[n][v][h] + head_b[n][v]
__global__ __launch_bounds__(256) void head_gemm(const float* __restrict__ hs,
                                                 const float* __restrict__ hw,
                                                 const float* __restrict__ hb,
                                                 float* __restrict__ out) {
    __shared__ float As[64][68];
    __shared__ float Ws[64][68];
    const int tid = threadIdx.x;
    const int tx = tid & 15, ty = tid >> 4;
    const int rb = blockIdx.x * 64;     // bt row base
    const int cb = blockIdx.y * 64;     // nv col base (0..383), whole tile in one head
    float acc[4][4] = {};
    for (int kb = 0; kb < Hh; kb += 64) {
        #pragma unroll
        for (int q = 0; q < 4; ++q) {
            int lin = q * 256 + tid;
            int row = lin >> 4;
            int c4 = (lin & 15) * 4;
            *(float4*)&As[row][c4] = *(const float4*)&hs[(size_t)(rb + row) * Hh + kb + c4];
            *(float4*)&Ws[row][c4] = *(const float4*)&hw[(size_t)(cb + row) * Hh + kb + c4];
        }
        __syncthreads();
        #pragma unroll 8
        for (int kk = 0; kk < 64; ++kk) {
            float a0 = As[ty*4+0][kk], a1 = As[ty*4+1][kk];
            float a2 = As[ty*4+2][kk], a3 = As[ty*4+3][kk];
            float w0 = Ws[tx*4+0][kk], w1 = Ws[tx*4+1][kk];
            float w2 = Ws[tx*4+2][kk], w3 = Ws[tx*4+3][kk];
            acc[0][0] += a0*w0; acc[0][1] += a0*w1; acc[0][2] += a0*w2; acc[0][3] += a0*w3;
            acc[1][0] += a1*w0; acc[1][1] += a1*w1; acc[1][2] += a1*w2; acc[1][3] += a1*w3;
            acc[2][0] += a2*w0; acc[2][1] += a2*w1; acc[2][2] += a2*w2; acc[2][3] += a2*w3;
            acc[3][0] += a3*w0; acc[3][1] += a3*w1; acc[3][2] += a3*w2; acc[3][3] += a3*w3;
        }
        __syncthreads();
    }
    const int n = cb >> 7;                 // which head (tile never straddles heads)
    const int v = (cb & 127) + tx * 4;     // v within head
    float bv0 = hb[n*Vv + v + 0];
    float bv1 = hb[n*Vv + v + 1];
    float bv2 = hb[n*Vv + v + 2];
    float bv3 = hb[n*Vv + v + 3];
    #pragma unroll
    for (int i = 0; i < 4; ++i) {
        int row = rb + ty * 4 + i;
        float4 r;
        r.x = acc[i][0] + bv0;
        r.y = acc[i][1] + bv1;
        r.z = acc[i][2] + bv2;
        r.w = acc[i][3] + bv3;
        *(float4*)&out[(size_t)n * BT * Vv + (size_t)row * Vv + v] = r;
    }
}

extern "C" void kernel_launch(void* const* d_in, const int* in_sizes, int n_in,
                              void* d_out, int out_size, void* d_ws, size_t ws_size,
                              hipStream_t stream) {
    const float* x    = (const float*)d_in[0];
    const float* Wih  = (const float*)d_in[1];
    const float* Whh  = (const float*)d_in[2];
    const float* bih  = (const float*)d_in[3];
    const float* bhh  = (const float*)d_in[4];
    const float* hw   = (const float*)d_in[5];
    const float* hb   = (const float*)d_in[6];
    float* out = (float*)d_out;

    float* gxw = (float*)d_ws;                         // [BT][1024] f32 = 256 MB
    float* hsw = gxw + (size_t)BT * G4;                // [BT][256]  f32 =  64 MB

    gx_gemm<<<dim3(BT/64, G4/64), 256, 0, stream>>>(x, Wih, bih, bhh, gxw);
    lstm_scan<<<Bb, 1024, 0, stream>>>(gxw, Whh, hsw);
    head_gemm<<<dim3(BT/64, (NVh*Vv)/64), 256, 0, stream>>>(hsw, hw, hb, out);
}

// Round 3
// 14155.006 us; speedup vs baseline: 1.3245x; 1.3245x over previous
//
#include <hip/hip_runtime.h>
#include <hip/hip_bf16.h>
#include <math.h>

#define Bb 64
#define Tt 1024
#define Dd 128
#define Hh 256
#define G4 1024  // 4*H
#define Vv 128
#define NVh 3
#define BT (Bb*Tt)

typedef __fp16 half2_t __attribute__((ext_vector_type(2)));

__device__ __forceinline__ half2_t pkh(float a, float b) {
    return __builtin_amdgcn_cvt_pkrtz(a, b);
}
__device__ __forceinline__ float fdot2(half2_t a, half2_t b, float c) {
#if __has_builtin(__builtin_amdgcn_fdot2)
    return __builtin_amdgcn_fdot2(a, b, c, false);
#else
    return c + (float)a[0] * (float)b[0] + (float)a[1] * (float)b[1];
#endif
}
__device__ __forceinline__ half2_t bch(unsigned int x) {
    return __builtin_bit_cast(half2_t, x);
}

// ---------------- Kernel A: gx[bt][j] = sum_d x[bt][d]*W_ih[j][d] + b_ih[j] + b_hh[j] ----
__global__ __launch_bounds__(256) void gx_gemm(const float* __restrict__ x,
                                               const float* __restrict__ Wih,
                                               const float* __restrict__ bih,
                                               const float* __restrict__ bhh,
                                               float* __restrict__ gx) {
    __shared__ float As[64][68];
    __shared__ float Ws[64][68];
    const int tid = threadIdx.x;
    const int tx = tid & 15, ty = tid >> 4;
    const int rb = blockIdx.x * 64;
    const int jb = blockIdx.y * 64;
    float acc[4][4] = {};
    for (int kb = 0; kb < Dd; kb += 64) {
        #pragma unroll
        for (int q = 0; q < 4; ++q) {
            int lin = q * 256 + tid;
            int row = lin >> 4;
            int c4 = (lin & 15) * 4;
            *(float4*)&As[row][c4] = *(const float4*)&x[(size_t)(rb + row) * Dd + kb + c4];
            *(float4*)&Ws[row][c4] = *(const float4*)&Wih[(size_t)(jb + row) * Dd + kb + c4];
        }
        __syncthreads();
        #pragma unroll 8
        for (int kk = 0; kk < 64; ++kk) {
            float a0 = As[ty*4+0][kk], a1 = As[ty*4+1][kk];
            float a2 = As[ty*4+2][kk], a3 = As[ty*4+3][kk];
            float w0 = Ws[tx*4+0][kk], w1 = Ws[tx*4+1][kk];
            float w2 = Ws[tx*4+2][kk], w3 = Ws[tx*4+3][kk];
            acc[0][0] += a0*w0; acc[0][1] += a0*w1; acc[0][2] += a0*w2; acc[0][3] += a0*w3;
            acc[1][0] += a1*w0; acc[1][1] += a1*w1; acc[1][2] += a1*w2; acc[1][3] += a1*w3;
            acc[2][0] += a2*w0; acc[2][1] += a2*w1; acc[2][2] += a2*w2; acc[2][3] += a2*w3;
            acc[3][0] += a3*w0; acc[3][1] += a3*w1; acc[3][2] += a3*w2; acc[3][3] += a3*w3;
        }
        __syncthreads();
    }
    const int col = jb + tx * 4;
    float bv0 = bih[col+0] + bhh[col+0];
    float bv1 = bih[col+1] + bhh[col+1];
    float bv2 = bih[col+2] + bhh[col+2];
    float bv3 = bih[col+3] + bhh[col+3];
    #pragma unroll
    for (int i = 0; i < 4; ++i) {
        int row = rb + ty * 4 + i;
        float4 r;
        r.x = acc[i][0] + bv0;
        r.y = acc[i][1] + bv1;
        r.z = acc[i][2] + bv2;
        r.w = acc[i][3] + bv3;
        *(float4*)&gx[(size_t)row * G4 + col] = r;
    }
}

// ---------------- Kernel B: persistent LSTM scan ----------------------------------
// 64 blocks (one per batch) x 256 threads (4 waves -> VGPR cap 512).
// Thread j owns gate rows {j, j+256, j+512, j+768}:
//   k in [0,224)  : 4 x 112 packed-f16 pairs = 448 VGPRs
//   k in [224,256): LDS, 64KB, lane-contiguous 16B chunks (conflict-free)
// h lives in LDS as f16; dots via v_dot2_f32_f16; c/h update fully thread-local.
__global__ __launch_bounds__(256, 1) void lstm_scan(const float* __restrict__ gx,
                                                    const float* __restrict__ Whh,
                                                    float* __restrict__ hs) {
    __shared__ __align__(16) uint4 wlds[16 * 256];   // 64KB  chunk c=r*4+q, lane j
    __shared__ __align__(16) __fp16 hsh[Hh];         // 512B
    const int j = threadIdx.x;
    const int b = blockIdx.x;

    // ---- stage W row slices: VGPR part (k<224) + LDS part (k>=224) ----
    half2_t w[4][112];
    #pragma unroll
    for (int r = 0; r < 4; ++r) {
        const float* wr = Whh + (size_t)(j + r * 256) * Hh;
        #pragma unroll
        for (int c = 0; c < 28; ++c) {
            float4 f0 = *(const float4*)&wr[c * 8];
            float4 f1 = *(const float4*)&wr[c * 8 + 4];
            w[r][c*4+0] = pkh(f0.x, f0.y);
            w[r][c*4+1] = pkh(f0.z, f0.w);
            w[r][c*4+2] = pkh(f1.x, f1.y);
            w[r][c*4+3] = pkh(f1.z, f1.w);
        }
        #pragma unroll
        for (int q = 0; q < 4; ++q) {
            float4 f0 = *(const float4*)&wr[224 + q * 8];
            float4 f1 = *(const float4*)&wr[224 + q * 8 + 4];
            uint4 o;
            o.x = __builtin_bit_cast(unsigned int, pkh(f0.x, f0.y));
            o.y = __builtin_bit_cast(unsigned int, pkh(f0.z, f0.w));
            o.z = __builtin_bit_cast(unsigned int, pkh(f1.x, f1.y));
            o.w = __builtin_bit_cast(unsigned int, pkh(f1.z, f1.w));
            wlds[(r * 4 + q) * 256 + j] = o;
        }
    }
    if (j < 128) ((unsigned int*)hsh)[j] = 0u;
    float c_state = 0.f;
    __syncthreads();

    const float* gxb = gx + (size_t)b * Tt * G4 + j;
    float* hsb = hs + (size_t)b * Tt * Hh + j;

    float g0 = gxb[0], g1 = gxb[256], g2 = gxb[512], g3 = gxb[768];

    for (int t = 0; t < Tt; ++t) {
        // prefetch next step's gx (independent of h) to hide HBM latency
        const float* gn = gxb + (size_t)(t + 1 < Tt ? t + 1 : t) * G4;
        float n0 = gn[0], n1 = gn[256], n2 = gn[512], n3 = gn[768];

        float a[4] = { g0, g1, g2, g3 };
        const uint4* h4 = (const uint4*)hsh;

        #pragma unroll
        for (int c = 0; c < 28; ++c) {
            uint4 hv = h4[c];                       // uniform broadcast read
            half2_t u0 = bch(hv.x), u1 = bch(hv.y);
            half2_t u2 = bch(hv.z), u3 = bch(hv.w);
            #pragma unroll
            for (int r = 0; r < 4; ++r) {
                a[r] = fdot2(w[r][c*4+0], u0, a[r]);
                a[r] = fdot2(w[r][c*4+1], u1, a[r]);
                a[r] = fdot2(w[r][c*4+2], u2, a[r]);
                a[r] = fdot2(w[r][c*4+3], u3, a[r]);
            }
        }
        // tail k in [224,256): W from LDS (lane-distinct, conflict-free)
        #pragma unroll
        for (int q = 0; q < 4; ++q) {
            uint4 hv = h4[28 + q];
            half2_t u0 = bch(hv.x), u1 = bch(hv.y);
            half2_t u2 = bch(hv.z), u3 = bch(hv.w);
            #pragma unroll
            for (int r = 0; r < 4; ++r) {
                uint4 wv = wlds[(r * 4 + q) * 256 + j];
                a[r] = fdot2(bch(wv.x), u0, a[r]);
                a[r] = fdot2(bch(wv.y), u1, a[r]);
                a[r] = fdot2(bch(wv.z), u2, a[r]);
                a[r] = fdot2(bch(wv.w), u3, a[r]);
            }
        }

        float ig = 1.f / (1.f + __expf(-a[0]));
        float fg = 1.f / (1.f + __expf(-a[1]));
        float tg = tanhf(a[2]);
        float og = 1.f / (1.f + __expf(-a[3]));
        c_state = fg * c_state + ig * tg;
        float hn = og * tanhf(c_state);

        __syncthreads();                 // all h reads for step t complete
        hsh[j] = (__fp16)hn;             // 2B write, race-free
        hsb[(size_t)t * Hh] = hn;        // f32 for the head GEMM
        g0 = n0; g1 = n1; g2 = n2; g3 = n3;
        __syncthreads();                 // h(t) visible for step t+1
    }
}

// ---------------- Kernel C: logits[n][bt][v] = sum_h hs[bt][h]*head_w[n][v][h] + head_b[n][v]
__global__ __launch_bounds__(256) void head_gemm(const float* __restrict__ hs,
                                                 const float* __restrict__ hw,
                                                 const float* __restrict__ hb,
                                                 float* __restrict__ out) {
    __shared__ float As[64][68];
    __shared__ float Ws[64][68];
    const int tid = threadIdx.x;
    const int tx = tid & 15, ty = tid >> 4;
    const int rb = blockIdx.x * 64;
    const int cb = blockIdx.y * 64;
    float acc[4][4] = {};
    for (int kb = 0; kb < Hh; kb += 64) {
        #pragma unroll
        for (int q = 0; q < 4; ++q) {
            int lin = q * 256 + tid;
            int row = lin >> 4;
            int c4 = (lin & 15) * 4;
            *(float4*)&As[row][c4] = *(const float4*)&hs[(size_t)(rb + row) * Hh + kb + c4];
            *(float4*)&Ws[row][c4] = *(const float4*)&hw[(size_t)(cb + row) * Hh + kb + c4];
        }
        __syncthreads();
        #pragma unroll 8
        for (int kk = 0; kk < 64; ++kk) {
            float a0 = As[ty*4+0][kk], a1 = As[ty*4+1][kk];
            float a2 = As[ty*4+2][kk], a3 = As[ty*4+3][kk];
            float w0 = Ws[tx*4+0][kk], w1 = Ws[tx*4+1][kk];
            float w2 = Ws[tx*4+2][kk], w3 = Ws[tx*4+3][kk];
            acc[0][0] += a0*w0; acc[0][1] += a0*w1; acc[0][2] += a0*w2; acc[0][3] += a0*w3;
            acc[1][0] += a1*w0; acc[1][1] += a1*w1; acc[1][2] += a1*w2; acc[1][3] += a1*w3;
            acc[2][0] += a2*w0; acc[2][1] += a2*w1; acc[2][2] += a2*w2; acc[2][3] += a2*w3;
            acc[3][0] += a3*w0; acc[3][1] += a3*w1; acc[3][2] += a3*w2; acc[3][3] += a3*w3;
        }
        __syncthreads();
    }
    const int n = cb >> 7;
    const int v = (cb & 127) + tx * 4;
    float bv0 = hb[n*Vv + v + 0];
    float bv1 = hb[n*Vv + v + 1];
    float bv2 = hb[n*Vv + v + 2];
    float bv3 = hb[n*Vv + v + 3];
    #pragma unroll
    for (int i = 0; i < 4; ++i) {
        int row = rb + ty * 4 + i;
        float4 r;
        r.x = acc[i][0] + bv0;
        r.y = acc[i][1] + bv1;
        r.z = acc[i][2] + bv2;
        r.w = acc[i][3] + bv3;
        *(float4*)&out[(size_t)n * BT * Vv + (size_t)row * Vv + v] = r;
    }
}

extern "C" void kernel_launch(void* const* d_in, const int* in_sizes, int n_in,
                              void* d_out, int out_size, void* d_ws, size_t ws_size,
                              hipStream_t stream) {
    const float* x    = (const float*)d_in[0];
    const float* Wih  = (const float*)d_in[1];
    const float* Whh  = (const float*)d_in[2];
    const float* bih  = (const float*)d_in[3];
    const float* bhh  = (const float*)d_in[4];
    const float* hw   = (const float*)d_in[5];
    const float* hb   = (const float*)d_in[6];
    float* out = (float*)d_out;

    float* gxw = (float*)d_ws;                         // [BT][1024] f32 = 256 MB
    float* hsw = gxw + (size_t)BT * G4;                // [BT][256]  f32 =  64 MB

    gx_gemm<<<dim3(BT/64, G4/64), 256, 0, stream>>>(x, Wih, bih, bhh, gxw);
    lstm_scan<<<Bb, 256, 0, stream>>>(gxw, Whh, hsw);
    head_gemm<<<dim3(BT/64, (NVh*Vv)/64), 256, 0, stream>>>(hsw, hw, hb, out);
}

// Round 4
// 2486.271 us; speedup vs baseline: 7.5405x; 5.6933x over previous
//
#include <hip/hip_runtime.h>
#include <hip/hip_bf16.h>
#include <math.h>

#define Bb 64
#define Tt 1024
#define Dd 128
#define Hh 256
#define G4 1024  // 4*H
#define Vv 128
#define NVh 3
#define BT (Bb*Tt)

typedef __fp16 half2_t __attribute__((ext_vector_type(2)));

__device__ __forceinline__ half2_t pkh(float a, float b) {
    return __builtin_amdgcn_cvt_pkrtz(a, b);
}
__device__ __forceinline__ float fdot2(half2_t a, half2_t b, float c) {
#if __has_builtin(__builtin_amdgcn_fdot2)
    return __builtin_amdgcn_fdot2(a, b, c, false);
#else
    return c + (float)a[0] * (float)b[0] + (float)a[1] * (float)b[1];
#endif
}
__device__ __forceinline__ half2_t bch(unsigned int x) {
    return __builtin_bit_cast(half2_t, x);
}

// ---------------- Kernel A: gx[bt][j] = sum_d x[bt][d]*W_ih[j][d] + b_ih[j] + b_hh[j] ----
__global__ __launch_bounds__(256) void gx_gemm(const float* __restrict__ x,
                                               const float* __restrict__ Wih,
                                               const float* __restrict__ bih,
                                               const float* __restrict__ bhh,
                                               float* __restrict__ gx) {
    __shared__ float As[64][68];
    __shared__ float Ws[64][68];
    const int tid = threadIdx.x;
    const int tx = tid & 15, ty = tid >> 4;
    const int rb = blockIdx.x * 64;
    const int jb = blockIdx.y * 64;
    float acc[4][4] = {};
    for (int kb = 0; kb < Dd; kb += 64) {
        #pragma unroll
        for (int q = 0; q < 4; ++q) {
            int lin = q * 256 + tid;
            int row = lin >> 4;
            int c4 = (lin & 15) * 4;
            *(float4*)&As[row][c4] = *(const float4*)&x[(size_t)(rb + row) * Dd + kb + c4];
            *(float4*)&Ws[row][c4] = *(const float4*)&Wih[(size_t)(jb + row) * Dd + kb + c4];
        }
        __syncthreads();
        #pragma unroll 8
        for (int kk = 0; kk < 64; ++kk) {
            float a0 = As[ty*4+0][kk], a1 = As[ty*4+1][kk];
            float a2 = As[ty*4+2][kk], a3 = As[ty*4+3][kk];
            float w0 = Ws[tx*4+0][kk], w1 = Ws[tx*4+1][kk];
            float w2 = Ws[tx*4+2][kk], w3 = Ws[tx*4+3][kk];
            acc[0][0] += a0*w0; acc[0][1] += a0*w1; acc[0][2] += a0*w2; acc[0][3] += a0*w3;
            acc[1][0] += a1*w0; acc[1][1] += a1*w1; acc[1][2] += a1*w2; acc[1][3] += a1*w3;
            acc[2][0] += a2*w0; acc[2][1] += a2*w1; acc[2][2] += a2*w2; acc[2][3] += a2*w3;
            acc[3][0] += a3*w0; acc[3][1] += a3*w1; acc[3][2] += a3*w2; acc[3][3] += a3*w3;
        }
        __syncthreads();
    }
    const int col = jb + tx * 4;
    float bv0 = bih[col+0] + bhh[col+0];
    float bv1 = bih[col+1] + bhh[col+1];
    float bv2 = bih[col+2] + bhh[col+2];
    float bv3 = bih[col+3] + bhh[col+3];
    #pragma unroll
    for (int i = 0; i < 4; ++i) {
        int row = rb + ty * 4 + i;
        float4 r;
        r.x = acc[i][0] + bv0;
        r.y = acc[i][1] + bv1;
        r.z = acc[i][2] + bv2;
        r.w = acc[i][3] + bv3;
        *(float4*)&gx[(size_t)row * G4 + col] = r;
    }
}

// ---------------- Kernel B: persistent LSTM scan (v3) ------------------------------
// 64 blocks (one per batch) x 512 threads (8 waves, 2/SIMD -> 256 VGPR cap).
// Thread j owns gate rows {j, j+512}:
//   k in [0,192)  : 2 x 96 packed-f16 pairs = 192 VGPRs (fits arch-VGPR limit!)
//   k in [192,256): LDS, 128KB, lane-contiguous uint4 (conflict-free)
// Gate pairing: thread j<256 has (i_j, g_j); thread j+256 has (f_j, o_j).
// f/o sigmoids cross via 2KB LDS exchange; c/h update on threads j<256.
__global__ __launch_bounds__(512, 2) void lstm_scan(const float* __restrict__ gx,
                                                    const float* __restrict__ Whh,
                                                    float* __restrict__ hs) {
    __shared__ __align__(16) uint4 wlds[16 * 512];   // 128KB: chunk r*8+q, lane j
    __shared__ __align__(16) __fp16 hsh[Hh];         // 512B
    __shared__ float gex[512];                       // 2KB: sf, so exchange
    const int j = threadIdx.x;
    const int b = blockIdx.x;

    // ---- stage W rows {j, j+512}: VGPR part (k<192) + LDS part (k>=192) ----
    half2_t w[2][96];
    #pragma unroll
    for (int r = 0; r < 2; ++r) {
        const float* wr = Whh + (size_t)(j + r * 512) * Hh;
        #pragma unroll
        for (int c = 0; c < 24; ++c) {
            float4 f0 = *(const float4*)&wr[c * 8];
            float4 f1 = *(const float4*)&wr[c * 8 + 4];
            w[r][c*4+0] = pkh(f0.x, f0.y);
            w[r][c*4+1] = pkh(f0.z, f0.w);
            w[r][c*4+2] = pkh(f1.x, f1.y);
            w[r][c*4+3] = pkh(f1.z, f1.w);
        }
        #pragma unroll
        for (int q = 0; q < 8; ++q) {
            float4 f0 = *(const float4*)&wr[192 + q * 8];
            float4 f1 = *(const float4*)&wr[192 + q * 8 + 4];
            uint4 o;
            o.x = __builtin_bit_cast(unsigned int, pkh(f0.x, f0.y));
            o.y = __builtin_bit_cast(unsigned int, pkh(f0.z, f0.w));
            o.z = __builtin_bit_cast(unsigned int, pkh(f1.x, f1.y));
            o.w = __builtin_bit_cast(unsigned int, pkh(f1.z, f1.w));
            wlds[(r * 8 + q) * 512 + j] = o;
        }
    }
    if (j < 128) ((unsigned int*)hsh)[j] = 0u;
    float c_state = 0.f;
    __syncthreads();

    const float* gxb = gx + (size_t)b * Tt * G4 + j;
    float* hsb = hs + (size_t)b * Tt * Hh + j;   // used only by j<256

    float g0 = gxb[0], g1 = gxb[512];

    for (int t = 0; t < Tt; ++t) {
        // prefetch next step's gx (independent of h)
        const float* gn = gxb + (size_t)(t + 1 < Tt ? t + 1 : t) * G4;
        float n0 = gn[0], n1 = gn[512];

        float a0 = g0, a1 = g1;
        const uint4* h4 = (const uint4*)hsh;

        #pragma unroll
        for (int c = 0; c < 24; ++c) {
            uint4 hv = h4[c];                       // uniform broadcast read
            half2_t u0 = bch(hv.x), u1 = bch(hv.y);
            half2_t u2 = bch(hv.z), u3 = bch(hv.w);
            a0 = fdot2(w[0][c*4+0], u0, a0); a1 = fdot2(w[1][c*4+0], u0, a1);
            a0 = fdot2(w[0][c*4+1], u1, a0); a1 = fdot2(w[1][c*4+1], u1, a1);
            a0 = fdot2(w[0][c*4+2], u2, a0); a1 = fdot2(w[1][c*4+2], u2, a1);
            a0 = fdot2(w[0][c*4+3], u3, a0); a1 = fdot2(w[1][c*4+3], u3, a1);
        }
        // tail k in [192,256): W from LDS (lane-distinct, conflict-free)
        #pragma unroll
        for (int q = 0; q < 8; ++q) {
            uint4 hv = h4[24 + q];
            half2_t u0 = bch(hv.x), u1 = bch(hv.y);
            half2_t u2 = bch(hv.z), u3 = bch(hv.w);
            uint4 w0 = wlds[q * 512 + j];
            uint4 w1 = wlds[(8 + q) * 512 + j];
            a0 = fdot2(bch(w0.x), u0, a0); a1 = fdot2(bch(w1.x), u0, a1);
            a0 = fdot2(bch(w0.y), u1, a0); a1 = fdot2(bch(w1.y), u1, a1);
            a0 = fdot2(bch(w0.z), u2, a0); a1 = fdot2(bch(w1.z), u2, a1);
            a0 = fdot2(bch(w0.w), u3, a0); a1 = fdot2(bch(w1.w), u3, a1);
        }

        float v0, v1;   // j<256: v0=si, v1=tg ; j>=256: v0=sf, v1=so
        if (j < 256) {
            v0 = 1.f / (1.f + __expf(-a0));
            v1 = tanhf(a1);
        } else {
            v0 = 1.f / (1.f + __expf(-a0));
            v1 = 1.f / (1.f + __expf(-a1));
            gex[j - 256] = v0;
            gex[j]       = v1;   // j-256+256
        }
        __syncthreads();                 // gex ready; all hsh reads complete
        if (j < 256) {
            float sf = gex[j];
            float so = gex[j + 256];
            c_state = sf * c_state + v0 * v1;
            float hn = so * tanhf(c_state);
            hsh[j] = (__fp16)hn;
            hsb[(size_t)t * Hh] = hn;
        }
        g0 = n0; g1 = n1;
        __syncthreads();                 // h(t) visible for step t+1
    }
}

// ---------------- Kernel C: logits[n][bt][v] = sum_h hs[bt][h]*head_w[n][v][h] + head_b[n][v]
__global__ __launch_bounds__(256) void head_gemm(const float* __restrict__ hs,
                                                 const float* __restrict__ hw,
                                                 const float* __restrict__ hb,
                                                 float* __restrict__ out) {
    __shared__ float As[64][68];
    __shared__ float Ws[64][68];
    const int tid = threadIdx.x;
    const int tx = tid & 15, ty = tid >> 4;
    const int rb = blockIdx.x * 64;
    const int cb = blockIdx.y * 64;
    float acc[4][4] = {};
    for (int kb = 0; kb < Hh; kb += 64) {
        #pragma unroll
        for (int q = 0; q < 4; ++q) {
            int lin = q * 256 + tid;
            int row = lin >> 4;
            int c4 = (lin & 15) * 4;
            *(float4*)&As[row][c4] = *(const float4*)&hs[(size_t)(rb + row) * Hh + kb + c4];
            *(float4*)&Ws[row][c4] = *(const float4*)&hw[(size_t)(cb + row) * Hh + kb + c4];
        }
        __syncthreads();
        #pragma unroll 8
        for (int kk = 0; kk < 64; ++kk) {
            float a0 = As[ty*4+0][kk], a1 = As[ty*4+1][kk];
            float a2 = As[ty*4+2][kk], a3 = As[ty*4+3][kk];
            float w0 = Ws[tx*4+0][kk], w1 = Ws[tx*4+1][kk];
            float w2 = Ws[tx*4+2][kk], w3 = Ws[tx*4+3][kk];
            acc[0][0] += a0*w0; acc[0][1] += a0*w1; acc[0][2] += a0*w2; acc[0][3] += a0*w3;
            acc[1][0] += a1*w0; acc[1][1] += a1*w1; acc[1][2] += a1*w2; acc[1][3] += a1*w3;
            acc[2][0] += a2*w0; acc[2][1] += a2*w1; acc[2][2] += a2*w2; acc[2][3] += a2*w3;
            acc[3][0] += a3*w0; acc[3][1] += a3*w1; acc[3][2] += a3*w2; acc[3][3] += a3*w3;
        }
        __syncthreads();
    }
    const int n = cb >> 7;
    const int v = (cb & 127) + tx * 4;
    float bv0 = hb[n*Vv + v + 0];
    float bv1 = hb[n*Vv + v + 1];
    float bv2 = hb[n*Vv + v + 2];
    float bv3 = hb[n*Vv + v + 3];
    #pragma unroll
    for (int i = 0; i < 4; ++i) {
        int row = rb + ty * 4 + i;
        float4 r;
        r.x = acc[i][0] + bv0;
        r.y = acc[i][1] + bv1;
        r.z = acc[i][2] + bv2;
        r.w = acc[i][3] + bv3;
        *(float4*)&out[(size_t)n * BT * Vv + (size_t)row * Vv + v] = r;
    }
}

extern "C" void kernel_launch(void* const* d_in, const int* in_sizes, int n_in,
                              void* d_out, int out_size, void* d_ws, size_t ws_size,
                              hipStream_t stream) {
    const float* x    = (const float*)d_in[0];
    const float* Wih  = (const float*)d_in[1];
    const float* Whh  = (const float*)d_in[2];
    const float* bih  = (const float*)d_in[3];
    const float* bhh  = (const float*)d_in[4];
    const float* hw   = (const float*)d_in[5];
    const float* hb   = (const float*)d_in[6];
    float* out = (float*)d_out;

    float* gxw = (float*)d_ws;                         // [BT][1024] f32 = 256 MB
    float* hsw = gxw + (size_t)BT * G4;                // [BT][256]  f32 =  64 MB

    gx_gemm<<<dim3(BT/64, G4/64), 256, 0, stream>>>(x, Wih, bih, bhh, gxw);
    lstm_scan<<<Bb, 512, 0, stream>>>(gxw, Whh, hsw);
    head_gemm<<<dim3(BT/64, (NVh*Vv)/64), 256, 0, stream>>>(hsw, hw, hb, out);
}